// Round 1
// baseline (1610.202 us; speedup 1.0000x reference)
//
#include <hip/hip_runtime.h>
#include <hip/hip_bf16.h>

#define N_NODES 50000
#define N_EDGES 800000
#define D 128
#define BN_EPS 1e-5f

// ---------------- kernel 1: degrees ----------------
__global__ __launch_bounds__(256) void deg_kernel(const int* __restrict__ src,
                                                  const int* __restrict__ dst,
                                                  int* __restrict__ deg_out,
                                                  int* __restrict__ deg_in) {
    int e = blockIdx.x * blockDim.x + threadIdx.x;
    if (e < N_EDGES) {
        atomicAdd(&deg_out[src[e]], 1);
        atomicAdd(&deg_in[dst[e]], 1);
    }
}

// ---------------- kernel 2: h = (feat * norm_src) @ W ----------------
// W staged in LDS (64 KB). Each 256-thread block processes 2 nodes per
// iteration: thread (sub,d) computes h[n][d].
__global__ __launch_bounds__(256) void proj_kernel(const float* __restrict__ feat,
                                                   const float* __restrict__ W,
                                                   const int* __restrict__ deg_out,
                                                   float* __restrict__ h) {
    __shared__ float Ws[D * D];   // 64 KB, [k][d]
    __shared__ float fs[2][D];
    for (int i = threadIdx.x; i < D * D; i += 256) Ws[i] = W[i];
    __syncthreads();

    const int d   = threadIdx.x & (D - 1);
    const int sub = threadIdx.x >> 7;       // 0 or 1

    for (int base = blockIdx.x * 2; base < N_NODES; base += gridDim.x * 2) {
        int n = base + sub;
        if (n < N_NODES) {
            int   deg = deg_out[n];
            float nrm = rsqrtf((float)(deg < 1 ? 1 : deg));
            fs[sub][d] = feat[(size_t)n * D + d] * nrm;
        }
        __syncthreads();
        if (n < N_NODES) {
            float acc = 0.f;
            #pragma unroll 8
            for (int k = 0; k < D; ++k)
                acc += fs[sub][k] * Ws[k * D + d];
            h[(size_t)n * D + d] = acc;
        }
        __syncthreads();
    }
}

// ---------------- kernel 3: agg[dst] += h[src] (SpMM) ----------------
// 32 threads per edge, each owns a float4 chunk of the 128-wide row.
__global__ __launch_bounds__(256) void agg_kernel(const int* __restrict__ src,
                                                  const int* __restrict__ dst,
                                                  const float* __restrict__ h,
                                                  float* __restrict__ agg) {
    long long tid = (long long)blockIdx.x * blockDim.x + threadIdx.x;
    int e = (int)(tid >> 5);
    int c = (int)(tid & 31);
    if (e < N_EDGES) {
        int s = src[e];
        int t = dst[e];
        float4 v = ((const float4*)(h + (size_t)s * D))[c];
        float* o = agg + (size_t)t * D + c * 4;
        atomicAdd(o + 0, v.x);
        atomicAdd(o + 1, v.y);
        atomicAdd(o + 2, v.z);
        atomicAdd(o + 3, v.w);
    }
}

// ---------------- kernel 4: dst-norm + bias + PReLU + BN partial sums ----
__global__ __launch_bounds__(256) void node_kernel(const float* __restrict__ agg,
                                                   const int* __restrict__ deg_in,
                                                   const float* __restrict__ b,
                                                   const float* __restrict__ a1,
                                                   float* __restrict__ h2,
                                                   float* __restrict__ bn_sum,
                                                   float* __restrict__ bn_sumsq) {
    const int d   = threadIdx.x & (D - 1);
    const int sub = threadIdx.x >> 7;
    const float alpha = a1[0];
    const float bias  = b[d];

    float lsum = 0.f, lsq = 0.f;
    for (int n = blockIdx.x * 2 + sub; n < N_NODES; n += gridDim.x * 2) {
        int   deg = deg_in[n];
        float nd  = rsqrtf((float)(deg < 1 ? 1 : deg));
        float x   = agg[(size_t)n * D + d] * nd + bias;
        x = (x >= 0.f) ? x : alpha * x;
        h2[(size_t)n * D + d] = x;
        lsum += x;
        lsq  += x * x;
    }

    __shared__ float s1[256], s2[256];
    s1[threadIdx.x] = lsum;
    s2[threadIdx.x] = lsq;
    __syncthreads();
    if (threadIdx.x < 128) {
        float a = s1[threadIdx.x] + s1[threadIdx.x + 128];
        float q = s2[threadIdx.x] + s2[threadIdx.x + 128];
        atomicAdd(&bn_sum[d], a);
        atomicAdd(&bn_sumsq[d], q);
    }
}

// ---------------- kernel 5: BN finalize + PReLU ----------------
__global__ __launch_bounds__(256) void final_kernel(const float* __restrict__ h2,
                                                    const float* __restrict__ bn_sum,
                                                    const float* __restrict__ bn_sumsq,
                                                    const float* __restrict__ gamma,
                                                    const float* __restrict__ beta,
                                                    const float* __restrict__ a2,
                                                    float* __restrict__ out) {
    int i = blockIdx.x * 256 + threadIdx.x;
    if (i < N_NODES * D) {
        int d = i & (D - 1);
        const float invN = 1.0f / (float)N_NODES;
        float mean = bn_sum[d] * invN;
        float var  = bn_sumsq[d] * invN - mean * mean;
        float inv  = rsqrtf(var + BN_EPS);
        float x = h2[i];
        x = (x - mean) * inv * gamma[d] + beta[d];
        float alpha = a2[0];
        out[i] = (x >= 0.f) ? x : alpha * x;
    }
}

extern "C" void kernel_launch(void* const* d_in, const int* in_sizes, int n_in,
                              void* d_out, int out_size, void* d_ws, size_t ws_size,
                              hipStream_t stream) {
    const float* feat  = (const float*)d_in[0];
    const int*   src   = (const int*)  d_in[1];
    const int*   dst   = (const int*)  d_in[2];
    const float* W     = (const float*)d_in[3];
    const float* b     = (const float*)d_in[4];
    const float* a1    = (const float*)d_in[5];
    const float* gamma = (const float*)d_in[6];
    const float* beta  = (const float*)d_in[7];
    const float* a2    = (const float*)d_in[8];
    float* out = (float*)d_out;

    // Workspace layout (bytes):
    //   [0,        200000)  deg_out  (int[50000])
    //   [200000,   400000)  deg_in   (int[50000])
    //   [400000, 26000000)  h        (float[50000*128])  (reused as h2)
    //   [26000000,51600000) agg      (float[50000*128])
    //   [51600000,51600512) bn_sum   (float[128])
    //   [51600512,51601024) bn_sumsq (float[128])
    char* ws = (char*)d_ws;
    int*   deg_out_p = (int*)(ws + 0);
    int*   deg_in_p  = (int*)(ws + 200000);
    float* h         = (float*)(ws + 400000);
    float* agg       = (float*)(ws + 26000000);
    float* bn_sum    = (float*)(ws + 51600000);
    float* bn_sumsq  = (float*)(ws + 51600512);

    // zero the accumulators (ws is poisoned 0xAA before every call)
    hipMemsetAsync(deg_out_p, 0, 2 * N_NODES * sizeof(int), stream);
    hipMemsetAsync(agg, 0, (size_t)N_NODES * D * sizeof(float), stream);
    hipMemsetAsync(bn_sum, 0, 1024, stream);

    // 1) degrees
    deg_kernel<<<(N_EDGES + 255) / 256, 256, 0, stream>>>(src, dst, deg_out_p, deg_in_p);

    // 2) projection
    proj_kernel<<<512, 256, 0, stream>>>(feat, W, deg_out_p, h);

    // 3) SpMM aggregation
    {
        long long threads = (long long)N_EDGES * 32;
        int blocks = (int)((threads + 255) / 256);
        agg_kernel<<<blocks, 256, 0, stream>>>(src, dst, h, agg);
    }

    // 4) node-wise norm/bias/PReLU + BN partial sums (h reused as h2)
    node_kernel<<<512, 256, 0, stream>>>(agg, deg_in_p, b, a1, h, bn_sum, bn_sumsq);

    // 5) BN finalize + PReLU
    final_kernel<<<(N_NODES * D + 255) / 256, 256, 0, stream>>>(h, bn_sum, bn_sumsq,
                                                                gamma, beta, a2, out);
}

// Round 2
// 432.720 us; speedup vs baseline: 3.7211x; 3.7211x over previous
//
#include <hip/hip_runtime.h>
#include <hip/hip_bf16.h>

#define N_NODES 50000
#define N_EDGES 800000
#define D 128
#define BN_EPS 1e-5f
#define SCAN_TILE 1024
#define N_TILES ((N_NODES + SCAN_TILE - 1) / SCAN_TILE)   // 49

// ---------------- kernel 1: degrees ----------------
__global__ __launch_bounds__(256) void deg_kernel(const int* __restrict__ src,
                                                  const int* __restrict__ dst,
                                                  int* __restrict__ deg_out,
                                                  int* __restrict__ deg_in) {
    int e = blockIdx.x * blockDim.x + threadIdx.x;
    if (e < N_EDGES) {
        atomicAdd(&deg_out[src[e]], 1);
        atomicAdd(&deg_in[dst[e]], 1);
    }
}

// ---------------- scan step 1: per-tile sums of deg_in ----------------
__global__ __launch_bounds__(256) void scan1_kernel(const int* __restrict__ deg,
                                                    int* __restrict__ partials) {
    __shared__ int s[256];
    int base = blockIdx.x * SCAN_TILE;
    int lsum = 0;
    for (int i = threadIdx.x; i < SCAN_TILE; i += 256) {
        int idx = base + i;
        lsum += (idx < N_NODES) ? deg[idx] : 0;
    }
    s[threadIdx.x] = lsum;
    __syncthreads();
    for (int off = 128; off > 0; off >>= 1) {
        if (threadIdx.x < off) s[threadIdx.x] += s[threadIdx.x + off];
        __syncthreads();
    }
    if (threadIdx.x == 0) partials[blockIdx.x] = s[0];
}

// ---------------- scan step 2: exclusive scan of tile sums (tiny) --------
__global__ void scan2_kernel(int* __restrict__ partials, int* __restrict__ row_ptr) {
    if (threadIdx.x == 0 && blockIdx.x == 0) {
        int acc = 0;
        for (int i = 0; i < N_TILES; ++i) {
            int v = partials[i];
            partials[i] = acc;
            acc += v;
        }
        row_ptr[N_NODES] = acc;   // == N_EDGES
    }
}

// ---------------- scan step 3: per-tile exclusive scan -> row_ptr,cursor --
__global__ __launch_bounds__(256) void scan3_kernel(const int* __restrict__ deg,
                                                    const int* __restrict__ partials,
                                                    int* __restrict__ row_ptr,
                                                    int* __restrict__ cursor) {
    __shared__ int s[256];
    int base = blockIdx.x * SCAN_TILE;
    int v[4];
    int lsum = 0;
    #pragma unroll
    for (int j = 0; j < 4; ++j) {
        int idx = base + threadIdx.x * 4 + j;
        v[j] = (idx < N_NODES) ? deg[idx] : 0;
        lsum += v[j];
    }
    s[threadIdx.x] = lsum;
    __syncthreads();
    // Hillis-Steele inclusive scan over 256 thread sums
    for (int off = 1; off < 256; off <<= 1) {
        int t = (threadIdx.x >= off) ? s[threadIdx.x - off] : 0;
        __syncthreads();
        s[threadIdx.x] += t;
        __syncthreads();
    }
    int run = partials[blockIdx.x] + s[threadIdx.x] - lsum;  // exclusive prefix
    #pragma unroll
    for (int j = 0; j < 4; ++j) {
        int idx = base + threadIdx.x * 4 + j;
        if (idx < N_NODES) {
            row_ptr[idx] = run;
            cursor[idx]  = run;
        }
        run += v[j];
    }
}

// ---------------- fill: bucket edges by dst ----------------
__global__ __launch_bounds__(256) void fill_kernel(const int* __restrict__ src,
                                                   const int* __restrict__ dst,
                                                   int* __restrict__ cursor,
                                                   int* __restrict__ esrc) {
    int e = blockIdx.x * 256 + threadIdx.x;
    if (e < N_EDGES) {
        int t = dst[e];
        int pos = atomicAdd(&cursor[t], 1);
        esrc[pos] = src[e];
    }
}

// ---------------- projection: h = (feat * norm_src) @ W ----------------
__global__ __launch_bounds__(256) void proj_kernel(const float* __restrict__ feat,
                                                   const float* __restrict__ W,
                                                   const int* __restrict__ deg_out,
                                                   float* __restrict__ h) {
    __shared__ float Ws[D * D];   // 64 KB, [k][d]
    __shared__ float fs[2][D];
    for (int i = threadIdx.x; i < D * D; i += 256) Ws[i] = W[i];
    __syncthreads();

    const int d   = threadIdx.x & (D - 1);
    const int sub = threadIdx.x >> 7;       // 0 or 1

    for (int base = blockIdx.x * 2; base < N_NODES; base += gridDim.x * 2) {
        int n = base + sub;
        if (n < N_NODES) {
            int   deg = deg_out[n];
            float nrm = rsqrtf((float)(deg < 1 ? 1 : deg));
            fs[sub][d] = feat[(size_t)n * D + d] * nrm;
        }
        __syncthreads();
        if (n < N_NODES) {
            float acc = 0.f;
            #pragma unroll 8
            for (int k = 0; k < D; ++k)
                acc += fs[sub][k] * Ws[k * D + d];
            h[(size_t)n * D + d] = acc;
        }
        __syncthreads();
    }
}

// ---------------- SpMM gather + dst-norm + bias + PReLU + BN partials ----
// 64 lanes per node, each lane owns a float2 of the 128-wide row.
__global__ __launch_bounds__(256) void spmm_kernel(const int* __restrict__ row_ptr,
                                                   const int* __restrict__ esrc,
                                                   const float* __restrict__ h,
                                                   const float* __restrict__ b,
                                                   const float* __restrict__ a1,
                                                   float* __restrict__ h2,
                                                   float* __restrict__ bn_sum,
                                                   float* __restrict__ bn_sumsq) {
    const int lane = threadIdx.x & 63;   // feature pair index
    const int grp  = threadIdx.x >> 6;   // 0..3 node subgroup
    const float alpha = a1[0];
    const float2 bias = ((const float2*)b)[lane];

    float lsum0 = 0.f, lsum1 = 0.f, lsq0 = 0.f, lsq1 = 0.f;

    for (int n = blockIdx.x * 4 + grp; n < N_NODES; n += gridDim.x * 4) {
        int beg = row_ptr[n];
        int end = row_ptr[n + 1];
        float a0 = 0.f, a1v = 0.f;
        int i = beg;
        for (; i + 1 < end; i += 2) {
            int s0 = esrc[i];
            int s1 = esrc[i + 1];
            float2 v0 = ((const float2*)(h + (size_t)s0 * D))[lane];
            float2 v1 = ((const float2*)(h + (size_t)s1 * D))[lane];
            a0  += v0.x + v1.x;
            a1v += v0.y + v1.y;
        }
        if (i < end) {
            int s0 = esrc[i];
            float2 v0 = ((const float2*)(h + (size_t)s0 * D))[lane];
            a0  += v0.x;
            a1v += v0.y;
        }
        int deg = end - beg;
        float nd = rsqrtf((float)(deg < 1 ? 1 : deg));
        float x0 = a0  * nd + bias.x;
        float x1 = a1v * nd + bias.y;
        x0 = (x0 >= 0.f) ? x0 : alpha * x0;
        x1 = (x1 >= 0.f) ? x1 : alpha * x1;
        ((float2*)(h2 + (size_t)n * D))[lane] = make_float2(x0, x1);
        lsum0 += x0; lsum1 += x1;
        lsq0  += x0 * x0; lsq1 += x1 * x1;
    }

    // reduce BN partials across the 4 node-subgroups in the block
    __shared__ float s[256];
    // sum0
    s[threadIdx.x] = lsum0; __syncthreads();
    if (grp == 0) atomicAdd(&bn_sum[lane * 2 + 0],
                            s[lane] + s[64 + lane] + s[128 + lane] + s[192 + lane]);
    __syncthreads();
    s[threadIdx.x] = lsum1; __syncthreads();
    if (grp == 0) atomicAdd(&bn_sum[lane * 2 + 1],
                            s[lane] + s[64 + lane] + s[128 + lane] + s[192 + lane]);
    __syncthreads();
    s[threadIdx.x] = lsq0; __syncthreads();
    if (grp == 0) atomicAdd(&bn_sumsq[lane * 2 + 0],
                            s[lane] + s[64 + lane] + s[128 + lane] + s[192 + lane]);
    __syncthreads();
    s[threadIdx.x] = lsq1; __syncthreads();
    if (grp == 0) atomicAdd(&bn_sumsq[lane * 2 + 1],
                            s[lane] + s[64 + lane] + s[128 + lane] + s[192 + lane]);
}

// ---------------- BN finalize + PReLU ----------------
__global__ __launch_bounds__(256) void final_kernel(const float* __restrict__ h2,
                                                    const float* __restrict__ bn_sum,
                                                    const float* __restrict__ bn_sumsq,
                                                    const float* __restrict__ gamma,
                                                    const float* __restrict__ beta,
                                                    const float* __restrict__ a2,
                                                    float* __restrict__ out) {
    int i = blockIdx.x * 256 + threadIdx.x;
    if (i < N_NODES * D) {
        int d = i & (D - 1);
        const float invN = 1.0f / (float)N_NODES;
        float mean = bn_sum[d] * invN;
        float var  = bn_sumsq[d] * invN - mean * mean;
        float inv  = rsqrtf(var + BN_EPS);
        float x = h2[i];
        x = (x - mean) * inv * gamma[d] + beta[d];
        float alpha = a2[0];
        out[i] = (x >= 0.f) ? x : alpha * x;
    }
}

extern "C" void kernel_launch(void* const* d_in, const int* in_sizes, int n_in,
                              void* d_out, int out_size, void* d_ws, size_t ws_size,
                              hipStream_t stream) {
    const float* feat  = (const float*)d_in[0];
    const int*   src   = (const int*)  d_in[1];
    const int*   dst   = (const int*)  d_in[2];
    const float* W     = (const float*)d_in[3];
    const float* b     = (const float*)d_in[4];
    const float* a1    = (const float*)d_in[5];
    const float* gamma = (const float*)d_in[6];
    const float* beta  = (const float*)d_in[7];
    const float* a2    = (const float*)d_in[8];
    float* out = (float*)d_out;

    // Workspace layout (bytes):
    char* ws = (char*)d_ws;
    int*   deg_out_p = (int*)(ws + 0);          // 200000
    int*   deg_in_p  = (int*)(ws + 200000);     // 200000
    int*   row_ptr   = (int*)(ws + 400000);     // 200004 (+pad)
    int*   cursor    = (int*)(ws + 600064);     // 200000
    int*   partials  = (int*)(ws + 800064);     // 256
    int*   esrc      = (int*)(ws + 800384);     // 3200000
    float* h         = (float*)(ws + 4000768);  // 25600000 (also reused as h2)
    float* h2        = h;                        // in-place ok (same layout, written after read? no:
                                                 // spmm reads h[src] and writes h2[n] -> must be
                                                 // DIFFERENT buffers. Use separate region:
    float* h2b       = (float*)(ws + 29601792); // 25600000
    float* bn_sum    = (float*)(ws + 55201792); // 512
    float* bn_sumsq  = (float*)(ws + 55202304); // 512

    // zero accumulators (ws is poisoned 0xAA before every call)
    hipMemsetAsync(deg_out_p, 0, 2 * N_NODES * sizeof(int), stream);
    hipMemsetAsync(bn_sum, 0, 1024, stream);

    // 1) degrees
    deg_kernel<<<(N_EDGES + 255) / 256, 256, 0, stream>>>(src, dst, deg_out_p, deg_in_p);

    // 2) CSR build: scan deg_in -> row_ptr, cursor
    scan1_kernel<<<N_TILES, 256, 0, stream>>>(deg_in_p, partials);
    scan2_kernel<<<1, 64, 0, stream>>>(partials, row_ptr);
    scan3_kernel<<<N_TILES, 256, 0, stream>>>(deg_in_p, partials, row_ptr, cursor);
    fill_kernel<<<(N_EDGES + 255) / 256, 256, 0, stream>>>(src, dst, cursor, esrc);

    // 3) projection
    proj_kernel<<<512, 256, 0, stream>>>(feat, W, deg_out_p, h);

    // 4) SpMM gather + fused node-wise ops + BN partials
    spmm_kernel<<<1024, 256, 0, stream>>>(row_ptr, esrc, h, b, a1, h2b, bn_sum, bn_sumsq);

    // 5) BN finalize + PReLU
    final_kernel<<<(N_NODES * D + 255) / 256, 256, 0, stream>>>(h2b, bn_sum, bn_sumsq,
                                                                gamma, beta, a2, out);
}

// Round 3
// 307.423 us; speedup vs baseline: 5.2377x; 1.4076x over previous
//
#include <hip/hip_runtime.h>
#include <hip/hip_bf16.h>

#define N_NODES 50000
#define N_EDGES 800000
#define D 128
#define BN_EPS 1e-5f
#define SCAN_TILE 1024
#define N_TILES ((N_NODES + SCAN_TILE - 1) / SCAN_TILE)   // 49
#define PROJ_LDK 136   // padded k-stride (ushorts) to break LDS bank conflicts

typedef __attribute__((ext_vector_type(8))) short bf16x8;
typedef __attribute__((ext_vector_type(4))) float f32x4;

__device__ inline float bf_lo(unsigned u) { union { unsigned x; float f; } c; c.x = u << 16; return c.f; }
__device__ inline float bf_hi(unsigned u) { union { unsigned x; float f; } c; c.x = u & 0xffff0000u; return c.f; }
__device__ inline unsigned short f2bf(float f) {
    union { float f; unsigned u; } c; c.f = f;
    unsigned u = c.u;
    u += 0x7fff + ((u >> 16) & 1);   // RNE
    return (unsigned short)(u >> 16);
}

// ---------------- kernel 1: degrees ----------------
__global__ __launch_bounds__(256) void deg_kernel(const int* __restrict__ src,
                                                  const int* __restrict__ dst,
                                                  int* __restrict__ deg_out,
                                                  int* __restrict__ deg_in) {
    int e = blockIdx.x * blockDim.x + threadIdx.x;
    if (e < N_EDGES) {
        atomicAdd(&deg_out[src[e]], 1);
        atomicAdd(&deg_in[dst[e]], 1);
    }
}

// ---------------- scan step 1: per-tile sums of deg_in ----------------
__global__ __launch_bounds__(256) void scan1_kernel(const int* __restrict__ deg,
                                                    int* __restrict__ partials) {
    __shared__ int s[256];
    int base = blockIdx.x * SCAN_TILE;
    int lsum = 0;
    for (int i = threadIdx.x; i < SCAN_TILE; i += 256) {
        int idx = base + i;
        lsum += (idx < N_NODES) ? deg[idx] : 0;
    }
    s[threadIdx.x] = lsum;
    __syncthreads();
    for (int off = 128; off > 0; off >>= 1) {
        if (threadIdx.x < off) s[threadIdx.x] += s[threadIdx.x + off];
        __syncthreads();
    }
    if (threadIdx.x == 0) partials[blockIdx.x] = s[0];
}

// ---------------- scan step 2: exclusive scan of tile sums (tiny) --------
__global__ void scan2_kernel(int* __restrict__ partials, int* __restrict__ row_ptr) {
    if (threadIdx.x == 0 && blockIdx.x == 0) {
        int acc = 0;
        for (int i = 0; i < N_TILES; ++i) {
            int v = partials[i];
            partials[i] = acc;
            acc += v;
        }
        row_ptr[N_NODES] = acc;   // == N_EDGES
    }
}

// ---------------- scan step 3: per-tile exclusive scan -> row_ptr,cursor --
__global__ __launch_bounds__(256) void scan3_kernel(const int* __restrict__ deg,
                                                    const int* __restrict__ partials,
                                                    int* __restrict__ row_ptr,
                                                    int* __restrict__ cursor) {
    __shared__ int s[256];
    int base = blockIdx.x * SCAN_TILE;
    int v[4];
    int lsum = 0;
    #pragma unroll
    for (int j = 0; j < 4; ++j) {
        int idx = base + threadIdx.x * 4 + j;
        v[j] = (idx < N_NODES) ? deg[idx] : 0;
        lsum += v[j];
    }
    s[threadIdx.x] = lsum;
    __syncthreads();
    for (int off = 1; off < 256; off <<= 1) {
        int t = (threadIdx.x >= off) ? s[threadIdx.x - off] : 0;
        __syncthreads();
        s[threadIdx.x] += t;
        __syncthreads();
    }
    int run = partials[blockIdx.x] + s[threadIdx.x] - lsum;  // exclusive prefix
    #pragma unroll
    for (int j = 0; j < 4; ++j) {
        int idx = base + threadIdx.x * 4 + j;
        if (idx < N_NODES) {
            row_ptr[idx] = run;
            cursor[idx]  = run;
        }
        run += v[j];
    }
}

// ---------------- fill: bucket edges by dst ----------------
__global__ __launch_bounds__(256) void fill_kernel(const int* __restrict__ src,
                                                   const int* __restrict__ dst,
                                                   int* __restrict__ cursor,
                                                   int* __restrict__ esrc) {
    int e = blockIdx.x * 256 + threadIdx.x;
    if (e < N_EDGES) {
        int t = dst[e];
        int pos = atomicAdd(&cursor[t], 1);
        esrc[pos] = src[e];
    }
}

// ---------------- projection: h = bf16((feat * norm_src) @ W) via MFMA ----
// Block = 256 thr = 4 waves. Each block-tile = 64 nodes x 128 dims.
// B fragments (W^T) cached in registers across tiles.
__global__ __launch_bounds__(256, 2) void proj_kernel(const float* __restrict__ feat,
                                                      const float* __restrict__ W,
                                                      const int* __restrict__ deg_out,
                                                      unsigned short* __restrict__ h) {
    __shared__ unsigned short Wt[D * PROJ_LDK];   // [d][k] bf16, padded
    __shared__ unsigned short As[64 * PROJ_LDK];  // [r][k] bf16, padded
    __shared__ float nrmS[64];

    const int tid  = threadIdx.x;
    const int wave = tid >> 6;
    const int lane = tid & 63;
    const int quad = lane >> 4;
    const int l16  = lane & 15;

    // stage Wt = W^T (bf16). W is [k][d] row-major.
    for (int idx = tid; idx < D * D; idx += 256) {
        int k = idx >> 7, d = idx & 127;
        Wt[d * PROJ_LDK + k] = f2bf(W[idx]);
    }
    __syncthreads();

    // preload B fragments: breg[dt][kk]; B[k][n]: n=l16, k=kk*32+quad*8+j
    bf16x8 breg[8][4];
    #pragma unroll
    for (int dt = 0; dt < 8; ++dt)
        #pragma unroll
        for (int kk = 0; kk < 4; ++kk)
            breg[dt][kk] = *(const bf16x8*)&Wt[(dt * 16 + l16) * PROJ_LDK + kk * 32 + quad * 8];

    const int n_tiles = (N_NODES + 63) / 64;
    for (int tile = blockIdx.x; tile < n_tiles; tile += gridDim.x) {
        const int base = tile * 64;
        __syncthreads();   // all waves done reading As from previous tile
        if (tid < 64) {
            int n = base + tid;
            int dg = (n < N_NODES) ? deg_out[n] : 1;
            nrmS[tid] = rsqrtf((float)(dg < 1 ? 1 : dg));
        }
        __syncthreads();
        for (int idx = tid; idx < 64 * 32; idx += 256) {
            int r = idx >> 5, c4 = idx & 31;
            int n = base + r;
            float4 v = (n < N_NODES) ? ((const float4*)(feat + (size_t)n * D))[c4]
                                     : make_float4(0.f, 0.f, 0.f, 0.f);
            float nm = nrmS[r];
            unsigned short* p = &As[r * PROJ_LDK + c4 * 4];
            p[0] = f2bf(v.x * nm); p[1] = f2bf(v.y * nm);
            p[2] = f2bf(v.z * nm); p[3] = f2bf(v.w * nm);
        }
        __syncthreads();

        f32x4 acc[8];
        #pragma unroll
        for (int dt = 0; dt < 8; ++dt) acc[dt] = (f32x4){0.f, 0.f, 0.f, 0.f};

        #pragma unroll
        for (int kk = 0; kk < 4; ++kk) {
            bf16x8 af = *(const bf16x8*)&As[(wave * 16 + l16) * PROJ_LDK + kk * 32 + quad * 8];
            #pragma unroll
            for (int dt = 0; dt < 8; ++dt)
                acc[dt] = __builtin_amdgcn_mfma_f32_16x16x32_bf16(af, breg[dt][kk], acc[dt], 0, 0, 0);
        }

        // C/D layout: col = lane&15, row = quad*4 + reg
        #pragma unroll
        for (int dt = 0; dt < 8; ++dt) {
            #pragma unroll
            for (int r = 0; r < 4; ++r) {
                int n = base + wave * 16 + quad * 4 + r;
                if (n < N_NODES)
                    h[(size_t)n * D + dt * 16 + l16] = f2bf(acc[dt][r]);
            }
        }
    }
}

// ---------------- SpMM gather (bf16 h) + norm + bias + PReLU + BN partials
// 16 lanes per node; each lane owns 8 dims (one 16B chunk).
#define ACC8(v) { acc[0] += bf_lo((v).x); acc[1] += bf_hi((v).x); \
                  acc[2] += bf_lo((v).y); acc[3] += bf_hi((v).y); \
                  acc[4] += bf_lo((v).z); acc[5] += bf_hi((v).z); \
                  acc[6] += bf_lo((v).w); acc[7] += bf_hi((v).w); }

__global__ __launch_bounds__(256) void spmm_kernel(const int* __restrict__ row_ptr,
                                                   const int* __restrict__ esrc,
                                                   const unsigned short* __restrict__ h,
                                                   const float* __restrict__ b,
                                                   const float* __restrict__ a1,
                                                   float* __restrict__ h2,
                                                   float* __restrict__ bn_sum,
                                                   float* __restrict__ bn_sumsq) {
    const int tid  = threadIdx.x;
    const int l16  = tid & 15;
    const int slot = (blockIdx.x * 256 + tid) >> 4;
    const int nslots = (gridDim.x * 256) >> 4;
    const float alpha = a1[0];
    const size_t coff = (size_t)l16 * 8;

    float bias[8];
    #pragma unroll
    for (int j = 0; j < 8; ++j) bias[j] = b[l16 * 8 + j];

    float lsum[8] = {0,0,0,0,0,0,0,0};
    float lsq[8]  = {0,0,0,0,0,0,0,0};

    for (int n = slot; n < N_NODES; n += nslots) {
        int beg = row_ptr[n];
        int end = row_ptr[n + 1];
        float acc[8] = {0,0,0,0,0,0,0,0};
        int i = beg;
        for (; i + 3 < end; i += 4) {
            uint4 v0 = *(const uint4*)(h + (size_t)esrc[i]     * D + coff);
            uint4 v1 = *(const uint4*)(h + (size_t)esrc[i + 1] * D + coff);
            uint4 v2 = *(const uint4*)(h + (size_t)esrc[i + 2] * D + coff);
            uint4 v3 = *(const uint4*)(h + (size_t)esrc[i + 3] * D + coff);
            ACC8(v0); ACC8(v1); ACC8(v2); ACC8(v3);
        }
        for (; i < end; ++i) {
            uint4 v0 = *(const uint4*)(h + (size_t)esrc[i] * D + coff);
            ACC8(v0);
        }
        int dg = end - beg;
        float nd = rsqrtf((float)(dg < 1 ? 1 : dg));
        float4 o0, o1;
        float x[8];
        #pragma unroll
        for (int j = 0; j < 8; ++j) {
            float xv = acc[j] * nd + bias[j];
            xv = (xv >= 0.f) ? xv : alpha * xv;
            x[j] = xv;
            lsum[j] += xv;
            lsq[j]  += xv * xv;
        }
        o0 = make_float4(x[0], x[1], x[2], x[3]);
        o1 = make_float4(x[4], x[5], x[6], x[7]);
        float4* po = (float4*)(h2 + (size_t)n * D + coff);
        po[0] = o0;
        po[1] = o1;
    }

    // reduce across the 4 slots within each wave (lanes differing in bits 4,5)
    #pragma unroll
    for (int j = 0; j < 8; ++j) {
        lsum[j] += __shfl_xor(lsum[j], 16);
        lsum[j] += __shfl_xor(lsum[j], 32);
        lsq[j]  += __shfl_xor(lsq[j], 16);
        lsq[j]  += __shfl_xor(lsq[j], 32);
    }

    __shared__ float red[4][256];
    const int wave = tid >> 6;
    const int lane = tid & 63;
    if (lane < 16) {
        #pragma unroll
        for (int j = 0; j < 8; ++j) {
            red[wave][l16 * 16 + j]     = lsum[j];
            red[wave][l16 * 16 + 8 + j] = lsq[j];
        }
    }
    __syncthreads();
    {
        float tot = red[0][tid] + red[1][tid] + red[2][tid] + red[3][tid];
        int l = tid >> 4;     // lane16 group
        int v = tid & 15;     // value index: 0..7 sum, 8..15 sumsq
        int dim = l * 8 + (v & 7);
        if (v < 8) atomicAdd(&bn_sum[dim], tot);
        else       atomicAdd(&bn_sumsq[dim], tot);
    }
}

// ---------------- BN finalize + PReLU (float4) ----------------
__global__ __launch_bounds__(256) void final_kernel(const float* __restrict__ h2,
                                                    const float* __restrict__ bn_sum,
                                                    const float* __restrict__ bn_sumsq,
                                                    const float* __restrict__ gamma,
                                                    const float* __restrict__ beta,
                                                    const float* __restrict__ a2,
                                                    float* __restrict__ out) {
    int i4 = blockIdx.x * 256 + threadIdx.x;
    if (i4 < N_NODES * D / 4) {
        int dbase = (i4 * 4) & (D - 1);
        const float invN = 1.0f / (float)N_NODES;
        const float alpha = a2[0];
        float4 x = ((const float4*)h2)[i4];
        float r[4] = {x.x, x.y, x.z, x.w};
        #pragma unroll
        for (int j = 0; j < 4; ++j) {
            int d = dbase + j;
            float mean = bn_sum[d] * invN;
            float var  = bn_sumsq[d] * invN - mean * mean;
            float inv  = rsqrtf(var + BN_EPS);
            float v = (r[j] - mean) * inv * gamma[d] + beta[d];
            r[j] = (v >= 0.f) ? v : alpha * v;
        }
        ((float4*)out)[i4] = make_float4(r[0], r[1], r[2], r[3]);
    }
}

extern "C" void kernel_launch(void* const* d_in, const int* in_sizes, int n_in,
                              void* d_out, int out_size, void* d_ws, size_t ws_size,
                              hipStream_t stream) {
    const float* feat  = (const float*)d_in[0];
    const int*   src   = (const int*)  d_in[1];
    const int*   dst   = (const int*)  d_in[2];
    const float* W     = (const float*)d_in[3];
    const float* b     = (const float*)d_in[4];
    const float* a1    = (const float*)d_in[5];
    const float* gamma = (const float*)d_in[6];
    const float* beta  = (const float*)d_in[7];
    const float* a2    = (const float*)d_in[8];
    float* out = (float*)d_out;

    // Workspace layout (bytes, 16B-aligned regions):
    char* ws = (char*)d_ws;
    int*            deg_out_p = (int*)(ws + 0);          // 200000
    int*            deg_in_p  = (int*)(ws + 200064);     // 200000
    int*            row_ptr   = (int*)(ws + 400384);     // 200004
    int*            cursor    = (int*)(ws + 600576);     // 200000
    int*            partials  = (int*)(ws + 800768);     // 256
    int*            esrc      = (int*)(ws + 801024);     // 3200000
    unsigned short* h         = (unsigned short*)(ws + 4001280);  // 12800000 (bf16)
    float*          h2        = (float*)(ws + 16801280); // 25600000
    float*          bn_sum    = (float*)(ws + 42401280); // 512
    float*          bn_sumsq  = (float*)(ws + 42401792); // 512

    // zero accumulators (ws is poisoned 0xAA before every call)
    hipMemsetAsync(deg_out_p, 0, 2 * N_NODES * sizeof(int) + 128, stream);
    hipMemsetAsync(bn_sum, 0, 1024, stream);

    // 1) degrees
    deg_kernel<<<(N_EDGES + 255) / 256, 256, 0, stream>>>(src, dst, deg_out_p, deg_in_p);

    // 2) CSR build over dst
    scan1_kernel<<<N_TILES, 256, 0, stream>>>(deg_in_p, partials);
    scan2_kernel<<<1, 64, 0, stream>>>(partials, row_ptr);
    scan3_kernel<<<N_TILES, 256, 0, stream>>>(deg_in_p, partials, row_ptr, cursor);
    fill_kernel<<<(N_EDGES + 255) / 256, 256, 0, stream>>>(src, dst, cursor, esrc);

    // 3) projection (MFMA bf16), h in bf16
    proj_kernel<<<512, 256, 0, stream>>>(feat, W, deg_out_p, h);

    // 4) SpMM gather + fused node-wise ops + BN partials
    spmm_kernel<<<2048, 256, 0, stream>>>(row_ptr, esrc, h, b, a1, h2, bn_sum, bn_sumsq);

    // 5) BN finalize + PReLU
    final_kernel<<<(N_NODES * D / 4 + 255) / 256, 256, 0, stream>>>(h2, bn_sum, bn_sumsq,
                                                                    gamma, beta, a2, out);
}